// Round 3
// baseline (2029.530 us; speedup 1.0000x reference)
//
#include <hip/hip_runtime.h>
#include <math.h>

// ---------------------------------------------------------------------------
// BlockAttnRes, round 3 (= round-2 design, hardened resubmit).
// 4-layer-fused per-token-persistent kernels. B=8, T=8192, D=128, L=16.
// Tokens=65536, per-token independent across ALL layers.
// 4 kernels: layers 0-3 -> P0, 4-7 -> P1, 8-11 -> P2, 12-15 -> out (h15).
// Per wave: 16 tokens; sources + running partial live in VGPRs for all 4
// layers. MFMA bf16 16x16x32 for both GEMMs; fp32 softmax/LN/accumulate.
// LDS: per-wave 8.5KB region (A-frags aliased with f32 v-transpose scratch);
// no __syncthreads anywhere (wave-private LDS, ordered by data deps).
// ---------------------------------------------------------------------------

typedef float    f32x4  __attribute__((ext_vector_type(4)));
typedef __bf16   bf16x8 __attribute__((ext_vector_type(8)));
typedef unsigned short u16x8 __attribute__((ext_vector_type(8)));

#define D 128

__device__ __forceinline__ unsigned short f2bf(float f) {
  unsigned int u = __builtin_bit_cast(unsigned int, f);
  u += 0x7fffu + ((u >> 16) & 1u);          // RNE
  return (unsigned short)(u >> 16);
}

__device__ __forceinline__ float dot4(f32x4 a, f32x4 b) {
  return a.x * b.x + a.y * b.y + a.z * b.z + a.w * b.w;
}

// exact-GELU via A&S 7.1.25 erf approx (|eps|<=2.5e-5, << bf16 rounding)
__device__ __forceinline__ float fast_gelu(float x) {
  float y = fabsf(x) * 0.70710678118654752f;
  float t = 1.0f / fmaf(0.47047f, y, 1.0f);
  float P = fmaf(fmaf(0.7478556f, t, -0.0958798f), t, 0.3480242f) * t;
  float E = __expf(-y * y);
  float er = fmaf(-P, E, 1.0f);             // erf(|x|/sqrt2)
  er = copysignf(er, x);
  return 0.5f * x * (1.0f + er);
}

// ---------------------------------------------------------------------------
// Pack W1/W2 (fp32 row-major) into bf16 MFMA B-fragment order:
// frag idx = ((kk*NT + nt)*64 + lane)*8 + j holds
//   B[k = kk*32 + (lane>>4)*8 + j][n = nt*16 + (lane&15)]
// so a B-fragment is ONE coalesced 16B load per lane at GEMM time.
// ---------------------------------------------------------------------------
__global__ __launch_bounds__(256) void pack_weights(
    const float* __restrict__ W1, const float* __restrict__ W2,
    unsigned short* __restrict__ W1p, unsigned short* __restrict__ W2p)
{
  int t = blockIdx.x * 256 + threadIdx.x;
  if (t < 16 * 128 * 256) {
    int layer = t >> 15, r = t & 32767;
    int j = r & 7, lane = (r >> 3) & 63, nt = (r >> 9) & 15, kk = (r >> 13) & 3;
    int k = kk * 32 + ((lane >> 4) << 3) + j;
    int n = (nt << 4) + (lane & 15);
    W1p[t] = f2bf(W1[(layer << 15) + (k << 8) + n]);     // W1: [128][256]
  } else {
    int t2 = t - 16 * 128 * 256;
    int layer = t2 >> 15, r = t2 & 32767;
    int j = r & 7, lane = (r >> 3) & 63, nt = (r >> 9) & 7, kk = (r >> 12) & 7;
    int k = kk * 32 + ((lane >> 4) << 3) + j;
    int n = (nt << 4) + (lane & 15);
    W2p[t2] = f2bf(W2[(layer << 15) + (k << 7) + n]);    // W2: [256][128]
  }
}

// ---------------------------------------------------------------------------
// 4-layer fused kernel. NS = number of committed block sources (1..4).
// Layers L0..L0+3 with L0 = 4*(NS-1). LAST: layer 15 writes h to dst and
// skips its (dead) MLP.
// ---------------------------------------------------------------------------
template<int NS, bool LAST>
__global__ __launch_bounds__(256)
void fused4(const float* __restrict__ S0, const float* __restrict__ S1,
            const float* __restrict__ S2, const float* __restrict__ S3,
            const float* __restrict__ wv_all, const float* __restrict__ lng_all,
            const float* __restrict__ lnb_all,
            const unsigned short* __restrict__ W1p, const float* __restrict__ b1_all,
            const unsigned short* __restrict__ W2p, const float* __restrict__ b2_all,
            float* __restrict__ dst)
{
  // per-wave 2176-float region: A-frags (u16; A1 = first 1024 f32-equiv,
  // A2 = first 2048) aliased with the 16x132 f32 v-transpose scratch.
  // Single-wave producer/consumer => DS program order suffices, no barrier.
  __shared__ float smem[4 * 2176];

  const int tid  = threadIdx.x;
  const int w    = tid >> 6;
  const int l    = tid & 63;
  const int rw   = l >> 2;            // wave-local token row 0..15
  const int sl   = l & 3;             // 32-col slice 0..3
  const int tok  = blockIdx.x * 64 + w * 16 + rw;
  const int c0   = sl * 32;
  const int ln15 = l & 15, lhi = l >> 4;

  float*          RG  = smem + w * 2176;
  u16x8*          RGf = (u16x8*)RG;
  unsigned short* RGu = (unsigned short*)RG;

  const float* srcs[4] = {S0, S1, S2, S3};

  // ---- load sources into registers; per-source inv-RMS once ---------------
  f32x4 V[NS][8];
  float rinv[NS];
  #pragma unroll
  for (int s = 0; s < NS; ++s) {
    const float* vp = srcs[s] + (size_t)tok * D + c0;
    float q = 0.f;
    #pragma unroll
    for (int i = 0; i < 8; ++i) {
      V[s][i] = *(const f32x4*)(vp + 4 * i);
      q += dot4(V[s][i], V[s][i]);
    }
    q += __shfl_xor(q, 1); q += __shfl_xor(q, 2);
    rinv[s] = rsqrtf(q * (1.f / 128.f) + 1e-8f);
  }

  f32x4 part[8];
  #pragma unroll
  for (int i = 0; i < 8; ++i) part[i] = f32x4{0.f, 0.f, 0.f, 0.f};

  const int L0 = (NS - 1) * 4;

  #pragma unroll 1                    // rolled: cuts code size 4x; cross-layer
  for (int ll = 0; ll < 4; ++ll) {    // ILP is blocked by the part-chain anyway
    const int layer = L0 + ll;

    const float* wl = wv_all + layer * D + c0;
    f32x4 wv[8];
    #pragma unroll
    for (int i = 0; i < 8; ++i) wv[i] = *(const f32x4*)(wl + 4 * i);

    // ---- mixture: softmax over sources (+ running partial), max-free:
    // |logit| <= |w|*sqrt(128) ~ 2.6, fp32 exp safe.
    float denom = 0.f;
    f32x4 hacc[8];
    #pragma unroll
    for (int i = 0; i < 8; ++i) hacc[i] = f32x4{0.f, 0.f, 0.f, 0.f};

    #pragma unroll
    for (int s = 0; s < NS; ++s) {
      float d2 = 0.f;
      #pragma unroll
      for (int i = 0; i < 8; ++i) d2 += dot4(wv[i], V[s][i]);
      d2 += __shfl_xor(d2, 1); d2 += __shfl_xor(d2, 2);
      float e = __expf(d2 * rinv[s]);
      denom += e;
      #pragma unroll
      for (int i = 0; i < 8; ++i) hacc[i] += e * V[s][i];
    }
    if (ll > 0) {
      float q = 0.f, d2 = 0.f;
      #pragma unroll
      for (int i = 0; i < 8; ++i) {
        q  += dot4(part[i], part[i]);
        d2 += dot4(wv[i], part[i]);
      }
      q  += __shfl_xor(q, 1);  q  += __shfl_xor(q, 2);
      d2 += __shfl_xor(d2, 1); d2 += __shfl_xor(d2, 2);
      float rp = rsqrtf(q * (1.f / 128.f) + 1e-8f);
      float e = __expf(d2 * rp);
      denom += e;
      #pragma unroll
      for (int i = 0; i < 8; ++i) hacc[i] += e * part[i];
    }
    float inv = 1.0f / denom;
    #pragma unroll
    for (int i = 0; i < 8; ++i) hacc[i] *= inv;        // h

    if (LAST && ll == 3) {                             // layer 15: MLP dead
      float* op = dst + (size_t)tok * D + c0;
      #pragma unroll
      for (int i = 0; i < 8; ++i) *(f32x4*)(op + 4 * i) = hacc[i];
      return;
    }

    // ---- LayerNorm (two-pass fp32) -> bf16 A1 fragments ------------------
    float sm = 0.f;
    #pragma unroll
    for (int i = 0; i < 8; ++i) sm += hacc[i].x + hacc[i].y + hacc[i].z + hacc[i].w;
    sm += __shfl_xor(sm, 1); sm += __shfl_xor(sm, 2);
    float mu = sm * (1.f / 128.f);
    float sv = 0.f;
    #pragma unroll
    for (int i = 0; i < 8; ++i) {
      f32x4 d4 = hacc[i] - mu;
      sv += dot4(d4, d4);
    }
    sv += __shfl_xor(sv, 1); sv += __shfl_xor(sv, 2);
    float rs = rsqrtf(sv * (1.f / 128.f) + 1e-5f);

    const float* gl = lng_all + layer * D;
    const float* bl = lnb_all + layer * D;
    #pragma unroll
    for (int hi = 0; hi < 4; ++hi) {
      f32x4 xa = (hacc[2 * hi]     - mu) * rs;
      f32x4 xb = (hacc[2 * hi + 1] - mu) * rs;
      f32x4 ga = *(const f32x4*)(gl + c0 + hi * 8);
      f32x4 gb = *(const f32x4*)(gl + c0 + hi * 8 + 4);
      f32x4 ba = *(const f32x4*)(bl + c0 + hi * 8);
      f32x4 bb = *(const f32x4*)(bl + c0 + hi * 8 + 4);
      xa = xa * ga + ba;  xb = xb * gb + bb;
      u16x8 pk;
      pk[0] = f2bf(xa.x); pk[1] = f2bf(xa.y); pk[2] = f2bf(xa.z); pk[3] = f2bf(xa.w);
      pk[4] = f2bf(xb.x); pk[5] = f2bf(xb.y); pk[6] = f2bf(xb.z); pk[7] = f2bf(xb.w);
      RGf[sl * 64 + hi * 16 + rw] = pk;       // A1[kk=sl][fraglane=hi*16+rw]
    }

    bf16x8 a1f[4];
    #pragma unroll
    for (int k = 0; k < 4; ++k)
      a1f[k] = __builtin_bit_cast(bf16x8, RGf[k * 64 + l]);

    // ---- GEMM1 (16x128 @ 128x256) + GELU -> A2 fragments -----------------
    const u16x8* W1f = (const u16x8*)(W1p + (size_t)layer * 32768);
    const float* b1l = b1_all + layer * 256;
    const f32x4 z4 = {0.f, 0.f, 0.f, 0.f};
    #pragma unroll
    for (int nt = 0; nt < 16; ++nt) {
      f32x4 a = z4;
      #pragma unroll
      for (int k = 0; k < 4; ++k) {
        bf16x8 bf = __builtin_bit_cast(bf16x8, W1f[(k * 16 + nt) * 64 + l]);
        a = __builtin_amdgcn_mfma_f32_16x16x32_bf16(a1f[k], bf, a, 0, 0, 0);
      }
      float bb1 = b1l[nt * 16 + ln15];
      int kk2 = nt >> 1;
      int hi2 = ((nt & 1) << 1) + (ln15 >> 3);
      #pragma unroll
      for (int r4 = 0; r4 < 4; ++r4) {
        float g = fast_gelu(a[r4] + bb1);
        RGu[((kk2 * 64 + hi2 * 16 + lhi * 4 + r4) << 3) + (l & 7)] = f2bf(g);
      }
    }

    bf16x8 a2f[8];
    #pragma unroll
    for (int k2 = 0; k2 < 8; ++k2)
      a2f[k2] = __builtin_bit_cast(bf16x8, RGf[k2 * 64 + l]);

    // ---- GEMM2 (16x256 @ 256x128) -> bank-swizzled LDS transpose ---------
    const u16x8* W2f = (const u16x8*)(W2p + (size_t)layer * 32768);
    const float* b2l = b2_all + layer * D;
    #pragma unroll
    for (int nt = 0; nt < 8; ++nt) {
      f32x4 a = z4;
      #pragma unroll
      for (int k2 = 0; k2 < 8; ++k2) {
        bf16x8 bf = __builtin_bit_cast(bf16x8, W2f[(k2 * 8 + nt) * 64 + l]);
        a = __builtin_amdgcn_mfma_f32_16x16x32_bf16(a2f[k2], bf, a, 0, 0, 0);
      }
      int n = nt * 16 + ln15;
      float bb2 = b2l[n];
      int phys = (n & 96) + ((n + ((n >> 5) << 3)) & 31);   // bank swizzle
      #pragma unroll
      for (int r4 = 0; r4 < 4; ++r4)
        RG[(lhi * 4 + r4) * 132 + phys] = a[r4] + bb2;
    }

    // ---- read back in token layout, accumulate running partial -----------
    #pragma unroll
    for (int i = 0; i < 8; ++i)
      part[i] += *(const f32x4*)(RG + rw * 132 + sl * 32 + ((4 * i + 8 * sl) & 31));
  }

  // ---- commit partial (P_b) in token layout, coalesced ---------------------
  float* op = dst + (size_t)tok * D + c0;
  #pragma unroll
  for (int i = 0; i < 8; ++i) *(f32x4*)(op + 4 * i) = part[i];
}

// ---------------------------------------------------------------------------
extern "C" void kernel_launch(void* const* d_in, const int* in_sizes, int n_in,
                              void* d_out, int out_size, void* d_ws, size_t ws_size,
                              hipStream_t stream)
{
  const float* emb = (const float*)d_in[0];
  const float* wv  = (const float*)d_in[1];
  const float* lng = (const float*)d_in[2];
  const float* lnb = (const float*)d_in[3];
  const float* W1  = (const float*)d_in[4];
  const float* b1  = (const float*)d_in[5];
  const float* W2  = (const float*)d_in[6];
  const float* b2  = (const float*)d_in[7];
  float* out = (float*)d_out;

  const int tokens = in_sizes[0] / D;                 // 65536
  const size_t tbytes = (size_t)tokens * D * sizeof(float);

  char* wsb = (char*)d_ws;
  float* P0 = (float*)(wsb + 0 * tbytes);
  float* P1 = (float*)(wsb + 1 * tbytes);
  float* P2 = (float*)(wsb + 2 * tbytes);
  unsigned short* W1p = (unsigned short*)(wsb + 3 * tbytes);
  unsigned short* W2p = W1p + 16 * 128 * 256;

  pack_weights<<<(16 * 128 * 256 * 2) / 256, 256, 0, stream>>>(W1, W2, W1p, W2p);

  const int grid = tokens / 64;
  fused4<1, false><<<grid, 256, 0, stream>>>(emb, nullptr, nullptr, nullptr,
      wv, lng, lnb, W1p, b1, W2p, b2, P0);
  fused4<2, false><<<grid, 256, 0, stream>>>(emb, P0, nullptr, nullptr,
      wv, lng, lnb, W1p, b1, W2p, b2, P1);
  fused4<3, false><<<grid, 256, 0, stream>>>(emb, P0, P1, nullptr,
      wv, lng, lnb, W1p, b1, W2p, b2, P2);
  fused4<4, true ><<<grid, 256, 0, stream>>>(emb, P0, P1, P2,
      wv, lng, lnb, W1p, b1, W2p, b2, out);
}

// Round 4
// 1456.552 us; speedup vs baseline: 1.3934x; 1.3934x over previous
//
#include <hip/hip_runtime.h>
#include <math.h>

// ---------------------------------------------------------------------------
// BlockAttnRes, round 4: 4-layer fusion kept, register pressure halved.
// 2 waves (1 block of 128) co-own 16 tokens: each wave holds 8 tokens of
// sources in regs (V[NS][4] = 64 VGPR max) and the pair splits the GEMM
// N-dimension. 3 __syncthreads per layer. Grid 4096.
// Round-3 failure mode: 16 tok/wave -> 230+ live regs -> AGPR/scratch ->
// 1 wave/SIMD residency -> 162us/wave latency serialization.
// ---------------------------------------------------------------------------

typedef float    f32x4  __attribute__((ext_vector_type(4)));
typedef __bf16   bf16x8 __attribute__((ext_vector_type(8)));
typedef unsigned short u16x8 __attribute__((ext_vector_type(8)));

#define D 128

__device__ __forceinline__ unsigned short f2bf(float f) {
  unsigned int u = __builtin_bit_cast(unsigned int, f);
  u += 0x7fffu + ((u >> 16) & 1u);          // RNE
  return (unsigned short)(u >> 16);
}

__device__ __forceinline__ float dot4(f32x4 a, f32x4 b) {
  return a.x * b.x + a.y * b.y + a.z * b.z + a.w * b.w;
}

// exact-GELU via A&S 7.1.25 erf approx (|eps|<=2.5e-5, << bf16 rounding)
__device__ __forceinline__ float fast_gelu(float x) {
  float y = fabsf(x) * 0.70710678118654752f;
  float t = 1.0f / fmaf(0.47047f, y, 1.0f);
  float P = fmaf(fmaf(0.7478556f, t, -0.0958798f), t, 0.3480242f) * t;
  float E = __expf(-y * y);
  float er = fmaf(-P, E, 1.0f);             // erf(|x|/sqrt2)
  er = copysignf(er, x);
  return 0.5f * x * (1.0f + er);
}

// ---------------------------------------------------------------------------
// Pack W1/W2 (fp32 row-major) into bf16 MFMA B-fragment order:
// frag idx = ((kk*NT + nt)*64 + lane)*8 + j holds
//   B[k = kk*32 + (lane>>4)*8 + j][n = nt*16 + (lane&15)]
// ---------------------------------------------------------------------------
__global__ __launch_bounds__(256) void pack_weights(
    const float* __restrict__ W1, const float* __restrict__ W2,
    unsigned short* __restrict__ W1p, unsigned short* __restrict__ W2p)
{
  int t = blockIdx.x * 256 + threadIdx.x;
  if (t < 16 * 128 * 256) {
    int layer = t >> 15, r = t & 32767;
    int j = r & 7, lane = (r >> 3) & 63, nt = (r >> 9) & 15, kk = (r >> 13) & 3;
    int k = kk * 32 + ((lane >> 4) << 3) + j;
    int n = (nt << 4) + (lane & 15);
    W1p[t] = f2bf(W1[(layer << 15) + (k << 8) + n]);     // W1: [128][256]
  } else {
    int t2 = t - 16 * 128 * 256;
    int layer = t2 >> 15, r = t2 & 32767;
    int j = r & 7, lane = (r >> 3) & 63, nt = (r >> 9) & 7, kk = (r >> 12) & 7;
    int k = kk * 32 + ((lane >> 4) << 3) + j;
    int n = (nt << 4) + (lane & 15);
    W2p[t2] = f2bf(W2[(layer << 15) + (k << 7) + n]);    // W2: [256][128]
  }
}

// ---------------------------------------------------------------------------
// 4-layer fused kernel, 16 tokens per 128-thread block (2 waves).
// Wave w2 owns token rows w2*8..w2*8+7 for the per-token phases and the
// N-half [w2*128, w2*128+128) / [w2*64, w2*64+64) of GEMM1/GEMM2.
// ---------------------------------------------------------------------------
template<int NS, bool LAST>
__global__ __launch_bounds__(128, 2)
void fused4(const float* __restrict__ S0, const float* __restrict__ S1,
            const float* __restrict__ S2, const float* __restrict__ S3,
            const float* __restrict__ wv_all, const float* __restrict__ lng_all,
            const float* __restrict__ lnb_all,
            const unsigned short* __restrict__ W1p, const float* __restrict__ b1_all,
            const unsigned short* __restrict__ W2p, const float* __restrict__ b2_all,
            float* __restrict__ dst)
{
  __shared__ u16x8 A1[256];     //  4 KB  A1 fragments (16x128 bf16)
  __shared__ u16x8 A2[512];     //  8 KB  A2 fragments (16x256 bf16)
  __shared__ float SC[2112];    //  8.25 KB  16x132 f32 v-transpose scratch

  const int tid  = threadIdx.x;
  const int w2   = tid >> 6;          // pair member 0/1
  const int l    = tid & 63;
  const int tk8  = l >> 3;            // wave-local token 0..7
  const int c8   = l & 7;             // 16-col slice 0..7
  const int r    = w2 * 8 + tk8;      // pair-local token row 0..15
  const int c0   = c8 * 16;
  const int tok  = blockIdx.x * 16 + r;
  const int ln15 = l & 15, lhi = l >> 4;

  unsigned short* A2u = (unsigned short*)A2;
  const float* srcs[4] = {S0, S1, S2, S3};

  // ---- load 8-token source slices into regs; per-source inv-RMS once ------
  f32x4 V[NS][4];
  float rinv[NS];
  #pragma unroll
  for (int s = 0; s < NS; ++s) {
    const float* vp = srcs[s] + (size_t)tok * D + c0;
    float q = 0.f;
    #pragma unroll
    for (int i = 0; i < 4; ++i) {
      V[s][i] = *(const f32x4*)(vp + 4 * i);
      q += dot4(V[s][i], V[s][i]);
    }
    q += __shfl_xor(q, 1); q += __shfl_xor(q, 2); q += __shfl_xor(q, 4);
    rinv[s] = rsqrtf(q * (1.f / 128.f) + 1e-8f);
  }

  f32x4 part[4];
  #pragma unroll
  for (int i = 0; i < 4; ++i) part[i] = f32x4{0.f, 0.f, 0.f, 0.f};

  const int L0 = (NS - 1) * 4;

  #pragma unroll 1
  for (int ll = 0; ll < 4; ++ll) {
    const int layer = L0 + ll;

    const float* wl = wv_all + layer * D + c0;
    f32x4 wv[4];
    #pragma unroll
    for (int i = 0; i < 4; ++i) wv[i] = *(const f32x4*)(wl + 4 * i);

    // ---- mixture softmax (max-free: |logit| <= ~2.6) ---------------------
    float denom = 0.f;
    f32x4 hacc[4];
    #pragma unroll
    for (int i = 0; i < 4; ++i) hacc[i] = f32x4{0.f, 0.f, 0.f, 0.f};

    #pragma unroll
    for (int s = 0; s < NS; ++s) {
      float d2 = 0.f;
      #pragma unroll
      for (int i = 0; i < 4; ++i) d2 += dot4(wv[i], V[s][i]);
      d2 += __shfl_xor(d2, 1); d2 += __shfl_xor(d2, 2); d2 += __shfl_xor(d2, 4);
      float e = __expf(d2 * rinv[s]);
      denom += e;
      #pragma unroll
      for (int i = 0; i < 4; ++i) hacc[i] += e * V[s][i];
    }
    if (ll > 0) {
      float q = 0.f, d2 = 0.f;
      #pragma unroll
      for (int i = 0; i < 4; ++i) {
        q  += dot4(part[i], part[i]);
        d2 += dot4(wv[i], part[i]);
      }
      q  += __shfl_xor(q, 1);  q  += __shfl_xor(q, 2);  q  += __shfl_xor(q, 4);
      d2 += __shfl_xor(d2, 1); d2 += __shfl_xor(d2, 2); d2 += __shfl_xor(d2, 4);
      float rp = rsqrtf(q * (1.f / 128.f) + 1e-8f);
      float e = __expf(d2 * rp);
      denom += e;
      #pragma unroll
      for (int i = 0; i < 4; ++i) hacc[i] += e * part[i];
    }
    float inv = 1.0f / denom;
    #pragma unroll
    for (int i = 0; i < 4; ++i) hacc[i] *= inv;        // h (this wave's 8 rows)

    if (LAST && ll == 3) {                             // layer 15: MLP dead
      float* op = dst + (size_t)tok * D + c0;
      #pragma unroll
      for (int i = 0; i < 4; ++i) *(f32x4*)(op + 4 * i) = hacc[i];
      return;
    }

    // ---- LayerNorm -> bf16 A1 fragments (XOR-swizzled LDS) ---------------
    float sm = 0.f;
    #pragma unroll
    for (int i = 0; i < 4; ++i) sm += hacc[i].x + hacc[i].y + hacc[i].z + hacc[i].w;
    sm += __shfl_xor(sm, 1); sm += __shfl_xor(sm, 2); sm += __shfl_xor(sm, 4);
    float mu = sm * (1.f / 128.f);
    float sv = 0.f;
    #pragma unroll
    for (int i = 0; i < 4; ++i) {
      f32x4 d4 = hacc[i] - mu;
      sv += dot4(d4, d4);
    }
    sv += __shfl_xor(sv, 1); sv += __shfl_xor(sv, 2); sv += __shfl_xor(sv, 4);
    float rs = rsqrtf(sv * (1.f / 128.f) + 1e-5f);

    const float* gl = lng_all + layer * D + c0;
    const float* bl = lnb_all + layer * D + c0;
    f32x4 xn[4];
    #pragma unroll
    for (int i = 0; i < 4; ++i) {
      f32x4 g4 = *(const f32x4*)(gl + 4 * i);
      f32x4 b4 = *(const f32x4*)(bl + 4 * i);
      xn[i] = (hacc[i] - mu) * rs * g4 + b4;
    }
    {
      u16x8 pk0, pk1;
      pk0[0]=f2bf(xn[0].x); pk0[1]=f2bf(xn[0].y); pk0[2]=f2bf(xn[0].z); pk0[3]=f2bf(xn[0].w);
      pk0[4]=f2bf(xn[1].x); pk0[5]=f2bf(xn[1].y); pk0[6]=f2bf(xn[1].z); pk0[7]=f2bf(xn[1].w);
      pk1[0]=f2bf(xn[2].x); pk1[1]=f2bf(xn[2].y); pk1[2]=f2bf(xn[2].z); pk1[3]=f2bf(xn[2].w);
      pk1[4]=f2bf(xn[3].x); pk1[5]=f2bf(xn[3].y); pk1[6]=f2bf(xn[3].z); pk1[7]=f2bf(xn[3].w);
      int kk  = c8 >> 1;
      int hi0 = (c8 & 1) * 2;
      int FL0 = hi0 * 16 + r, FL1 = (hi0 + 1) * 16 + r;
      A1[kk * 64 + (FL0 ^ kk)] = pk0;      // xn[r][kk*32 + hi0*8 + 0..7]
      A1[kk * 64 + (FL1 ^ kk)] = pk1;      // xn[r][kk*32 + hi0*8 + 8..15]
    }
    __syncthreads();                                       // A1 ready

    bf16x8 a1f[4];
    #pragma unroll
    for (int k = 0; k < 4; ++k)
      a1f[k] = __builtin_bit_cast(bf16x8, A1[k * 64 + (l ^ k)]);

    // ---- GEMM1 (16x128 @ 128x256), this wave's N-half + GELU -> A2 -------
    const u16x8* W1f = (const u16x8*)(W1p + (size_t)layer * 32768);
    const float* b1l = b1_all + layer * 256;
    const f32x4 z4 = {0.f, 0.f, 0.f, 0.f};
    #pragma unroll
    for (int nti = 0; nti < 8; ++nti) {
      int nt = w2 * 8 + nti;
      f32x4 a = z4;
      #pragma unroll
      for (int k = 0; k < 4; ++k) {
        bf16x8 bf = __builtin_bit_cast(bf16x8, W1f[(k * 16 + nt) * 64 + l]);
        a = __builtin_amdgcn_mfma_f32_16x16x32_bf16(a1f[k], bf, a, 0, 0, 0);
      }
      float bb1 = b1l[nt * 16 + ln15];
      int kk2 = nt >> 1;
      int hi2 = ((nt & 1) << 1) + (ln15 >> 3);
      #pragma unroll
      for (int r4 = 0; r4 < 4; ++r4) {
        float g = fast_gelu(a[r4] + bb1);
        int FL = hi2 * 16 + lhi * 4 + r4;
        A2u[((kk2 * 64 + (FL ^ kk2)) << 3) + (l & 7)] = f2bf(g);
      }
    }
    __syncthreads();                                       // A2 ready

    bf16x8 a2f[8];
    #pragma unroll
    for (int k2 = 0; k2 < 8; ++k2)
      a2f[k2] = __builtin_bit_cast(bf16x8, A2[k2 * 64 + (l ^ k2)]);

    // ---- GEMM2 (16x256 @ 256x128), this wave's N-quarter -----------------
    const u16x8* W2f = (const u16x8*)(W2p + (size_t)layer * 32768);
    const float* b2l = b2_all + layer * D;
    #pragma unroll
    for (int nti = 0; nti < 4; ++nti) {
      int nt2 = w2 * 4 + nti;
      f32x4 a = z4;
      #pragma unroll
      for (int k2 = 0; k2 < 8; ++k2) {
        bf16x8 bf = __builtin_bit_cast(bf16x8, W2f[(k2 * 8 + nt2) * 64 + l]);
        a = __builtin_amdgcn_mfma_f32_16x16x32_bf16(a2f[k2], bf, a, 0, 0, 0);
      }
      int n = nt2 * 16 + ln15;
      float bb2 = b2l[n];
      int phys = (n & 96) + ((n + ((n >> 5) << 3)) & 31);   // bank-rotated col
      #pragma unroll
      for (int r4 = 0; r4 < 4; ++r4)
        SC[(lhi * 4 + r4) * 132 + phys] = a[r4] + bb2;
    }
    __syncthreads();                                       // v ready

    // ---- read v back in token layout, accumulate running partial ---------
    #pragma unroll
    for (int i = 0; i < 4; ++i) {
      int c = c0 + 4 * i;
      part[i] += *(const f32x4*)(SC + r * 132 + (c & 96) + ((c + ((c >> 5) << 3)) & 31));
    }
  }

  // ---- commit partial (P_b) in token layout, coalesced ---------------------
  float* op = dst + (size_t)tok * D + c0;
  #pragma unroll
  for (int i = 0; i < 4; ++i) *(f32x4*)(op + 4 * i) = part[i];
}

// ---------------------------------------------------------------------------
extern "C" void kernel_launch(void* const* d_in, const int* in_sizes, int n_in,
                              void* d_out, int out_size, void* d_ws, size_t ws_size,
                              hipStream_t stream)
{
  const float* emb = (const float*)d_in[0];
  const float* wv  = (const float*)d_in[1];
  const float* lng = (const float*)d_in[2];
  const float* lnb = (const float*)d_in[3];
  const float* W1  = (const float*)d_in[4];
  const float* b1  = (const float*)d_in[5];
  const float* W2  = (const float*)d_in[6];
  const float* b2  = (const float*)d_in[7];
  float* out = (float*)d_out;

  const int tokens = in_sizes[0] / D;                 // 65536
  const size_t tbytes = (size_t)tokens * D * sizeof(float);

  char* wsb = (char*)d_ws;
  float* P0 = (float*)(wsb + 0 * tbytes);
  float* P1 = (float*)(wsb + 1 * tbytes);
  float* P2 = (float*)(wsb + 2 * tbytes);
  unsigned short* W1p = (unsigned short*)(wsb + 3 * tbytes);
  unsigned short* W2p = W1p + 16 * 128 * 256;

  pack_weights<<<(16 * 128 * 256 * 2) / 256, 256, 0, stream>>>(W1, W2, W1p, W2p);

  const int grid = tokens / 16;                       // 4096 blocks of 128
  fused4<1, false><<<grid, 128, 0, stream>>>(emb, nullptr, nullptr, nullptr,
      wv, lng, lnb, W1p, b1, W2p, b2, P0);
  fused4<2, false><<<grid, 128, 0, stream>>>(emb, P0, nullptr, nullptr,
      wv, lng, lnb, W1p, b1, W2p, b2, P1);
  fused4<3, false><<<grid, 128, 0, stream>>>(emb, P0, P1, nullptr,
      wv, lng, lnb, W1p, b1, W2p, b2, P2);
  fused4<4, true ><<<grid, 128, 0, stream>>>(emb, P0, P1, P2,
      wv, lng, lnb, W1p, b1, W2p, b2, out);
}